// Round 8
// baseline (367.112 us; speedup 1.0000x reference)
//
#include <hip/hip_runtime.h>
#include <hip/hip_bf16.h>
#include <math.h>

#define L_TOT 1024
#define HD 256
#define LDQKV 2560   // fused Q|K|V row width (bf16): 2048 Q + 256 K + 256 V

typedef __bf16 bf16x8 __attribute__((ext_vector_type(8)));
typedef __bf16 bf16x4 __attribute__((ext_vector_type(4)));
typedef _Float16 f16x4 __attribute__((ext_vector_type(4)));
typedef float f32x4 __attribute__((ext_vector_type(4)));

__device__ __forceinline__ void gld_lds16(const __bf16* g, __bf16* l) {
  __builtin_amdgcn_global_load_lds(
      (const __attribute__((address_space(1))) void*)g,
      (__attribute__((address_space(3))) void*)l, 16, 0, 0);
}

// ======================= PREP: all weight transposes + activation cvts =======================
__device__ __forceinline__ void do_cvt(const float* __restrict__ in, __bf16* __restrict__ out,
                                       int i) {
  float4 v = ((const float4*)in)[i];
  bf16x4 o;
  o[0] = (__bf16)v.x; o[1] = (__bf16)v.y; o[2] = (__bf16)v.z; o[3] = (__bf16)v.w;
  ((bf16x4*)out)[i] = o;
}

__device__ __forceinline__ void do_cvt_h(const float* __restrict__ in, _Float16* __restrict__ out,
                                         int i) {
  float4 v = ((const float4*)in)[i];
  f16x4 o;
  o[0] = (_Float16)v.x; o[1] = (_Float16)v.y; o[2] = (_Float16)v.z; o[3] = (_Float16)v.w;
  ((f16x4*)out)[i] = o;
}

__device__ __forceinline__ void do_transpose(const float* __restrict__ W, __bf16* __restrict__ Wt,
                                             int K, int N, int rem, int tid, float (*t)[33]) {
  const int tiles_x = N >> 5;
  const int n0 = (rem % tiles_x) * 32, k0 = (rem / tiles_x) * 32;
  const int tx = tid & 31, ty = tid >> 5;  // ty 0..7
#pragma unroll
  for (int r = 0; r < 32; r += 8)
    t[ty + r][tx] = W[(size_t)(k0 + ty + r) * N + n0 + tx];
  __syncthreads();
#pragma unroll
  for (int r = 0; r < 32; r += 8)
    Wt[(size_t)(n0 + ty + r) * K + k0 + tx] = (__bf16)t[tx][ty + r];
}

// segments (cumulative blocks): cvt_pali 6144 | cvt_expe 1024 | wq_p 4096 | wk_p 512 |
// wv_p 512 | wq_e 2048 | wk_e 256 | wv_e 256 | wo_p 4096 | wo_e 2048 | mask_cvt 4096 => 25088
__global__ __launch_bounds__(256) void prep_kernel(
    const float* __restrict__ pali, const float* __restrict__ expe,
    const float* __restrict__ wq_p, const float* __restrict__ wk_p, const float* __restrict__ wv_p,
    const float* __restrict__ wq_e, const float* __restrict__ wk_e, const float* __restrict__ wv_e,
    const float* __restrict__ wo_p, const float* __restrict__ wo_e,
    const float* __restrict__ mask,
    __bf16* __restrict__ palib, __bf16* __restrict__ expeb,
    __bf16* __restrict__ WqkvpT, __bf16* __restrict__ WqkveT,
    __bf16* __restrict__ WopT, __bf16* __restrict__ WoeT,
    _Float16* __restrict__ maskh)
{
  __shared__ float t[32][33];
  const int bid = blockIdx.x, tid = threadIdx.x;
  if      (bid <  6144) do_cvt(pali, palib, bid * 256 + tid);
  else if (bid <  7168) do_cvt(expe, expeb, (bid - 6144) * 256 + tid);
  else if (bid < 11264) do_transpose(wq_p, WqkvpT,                       2048, 2048, bid - 7168,  tid, t);
  else if (bid < 11776) do_transpose(wk_p, WqkvpT + (size_t)2048 * 2048, 2048,  256, bid - 11264, tid, t);
  else if (bid < 12288) do_transpose(wv_p, WqkvpT + (size_t)2304 * 2048, 2048,  256, bid - 11776, tid, t);
  else if (bid < 14336) do_transpose(wq_e, WqkveT,                       1024, 2048, bid - 12288, tid, t);
  else if (bid < 14592) do_transpose(wk_e, WqkveT + (size_t)2048 * 1024, 1024,  256, bid - 14336, tid, t);
  else if (bid < 14848) do_transpose(wv_e, WqkveT + (size_t)2304 * 1024, 1024,  256, bid - 14592, tid, t);
  else if (bid < 18944) do_transpose(wo_p, WopT,                         2048, 2048, bid - 14848, tid, t);
  else if (bid < 20992) do_transpose(wo_e, WoeT,                         2048, 1024, bid - 18944, tid, t);
  else                  do_cvt_h(mask, maskh, (bid - 20992) * 256 + tid);
}

// ======================= bf16 MFMA GEMM body (m97 structure) =======================
template <typename OutT>
__device__ __forceinline__ void gemm_body(
    const __bf16* __restrict__ A, const __bf16* __restrict__ Wt, OutT* __restrict__ C,
    int La, int K, int A_Ls, int A_off, int C_Ls, int C_off, int ldc,
    int m0, int n0, __bf16* As, __bf16* Bs, int tid)
{
  const int wave = tid >> 6, lane = tid & 63;
  const int lrow = lane >> 2;
  const int k8   = lane & 3;

  const __bf16 *ag0, *ag1;
  {
    int m_a0 = m0 + wave * 16 + lrow;
    int m_a1 = m_a0 + 64;
    int b0 = m_a0 / La, b1 = m_a1 / La;
    ag0 = A + (size_t)(b0 * A_Ls + A_off + m_a0 - b0 * La) * K + k8 * 8;
    ag1 = A + (size_t)(b1 * A_Ls + A_off + m_a1 - b1 * La) * K + k8 * 8;
  }
  const __bf16* bg0 = Wt + (size_t)(n0 + wave * 16 + lrow) * K + k8 * 8;
  const __bf16* bg1 = bg0 + (size_t)64 * K;
  __bf16* al0 = As + wave * 512;
  __bf16* al1 = As + (4 + wave) * 512;
  __bf16* bl0 = Bs + wave * 512;
  __bf16* bl1 = Bs + (4 + wave) * 512;

  const int wm = (wave & 1) * 64, wn = (wave >> 1) * 64;
  const int fr = lane & 15, quad = lane >> 4;

  f32x4 acc[4][4];
#pragma unroll
  for (int i = 0; i < 4; ++i)
#pragma unroll
    for (int j = 0; j < 4; ++j) acc[i][j] = (f32x4){0.f, 0.f, 0.f, 0.f};

  for (int kk = 0; kk < K; kk += 32) {
    gld_lds16(ag0 + kk, al0);
    gld_lds16(ag1 + kk, al1);
    gld_lds16(bg0 + kk, bl0);
    gld_lds16(bg1 + kk, bl1);
    __syncthreads();
    bf16x8 af[4], bfr[4];
#pragma unroll
    for (int mt = 0; mt < 4; ++mt)
      af[mt] = *(const bf16x8*)(As + (wm + mt * 16 + fr) * 32 + quad * 8);
#pragma unroll
    for (int nt = 0; nt < 4; ++nt)
      bfr[nt] = *(const bf16x8*)(Bs + (wn + nt * 16 + fr) * 32 + quad * 8);
#pragma unroll
    for (int mt = 0; mt < 4; ++mt)
#pragma unroll
      for (int nt = 0; nt < 4; ++nt)
        acc[mt][nt] = __builtin_amdgcn_mfma_f32_16x16x32_bf16(af[mt], bfr[nt], acc[mt][nt], 0, 0, 0);
    __syncthreads();
  }

#pragma unroll
  for (int mt = 0; mt < 4; ++mt) {
#pragma unroll
    for (int r = 0; r < 4; ++r) {
      int m = m0 + wm + mt * 16 + quad * 4 + r;
      int b = m / La;
      OutT* crow = C + (size_t)(b * C_Ls + C_off + m - b * La) * ldc + n0 + wn + fr;
#pragma unroll
      for (int nt = 0; nt < 4; ++nt) crow[nt * 16] = (OutT)acc[mt][nt][r];
    }
  }
}

// Merged QKV projection with XCD-chunked swizzle (T1): 640 blocks, chunk=80 per XCD.
// Each XCD owns contiguous idx => fixed-m n-sweeps reuse the A panel in its private L2.
__global__ __launch_bounds__(256) void gemm_qkv_kernel(
    const __bf16* __restrict__ palib, const __bf16* __restrict__ expeb,
    const __bf16* __restrict__ WqkvpT, const __bf16* __restrict__ WqkveT,
    __bf16* __restrict__ QKV)
{
  __shared__ __bf16 As[128 * 32];
  __shared__ __bf16 Bs[128 * 32];
  const int raw = blockIdx.x, tid = threadIdx.x;
  const int idx = (raw & 7) * 80 + (raw >> 3);   // 640/8 = 80, bijective
  if (idx < 480) {
    gemm_body<__bf16>(palib, WqkvpT, QKV, 768, 2048, 768, 0, L_TOT, 0, LDQKV,
                      (idx / 20) * 128, (idx % 20) * 128, As, Bs, tid);
  } else {
    int j = idx - 480;
    gemm_body<__bf16>(expeb, WqkveT, QKV, 256, 1024, 256, 0, L_TOT, 768, LDQKV,
                      (j / 20) * 128, (j % 20) * 128, As, Bs, tid);
  }
}

// Merged output projection with XCD-chunked swizzle: 448 blocks, chunk=56 per XCD.
__global__ __launch_bounds__(256) void gemm_out_kernel(
    const __bf16* __restrict__ Ab, const __bf16* __restrict__ WopT,
    const __bf16* __restrict__ WoeT, float* __restrict__ out)
{
  __shared__ __bf16 As[128 * 32];
  __shared__ __bf16 Bs[128 * 32];
  const int raw = blockIdx.x, tid = threadIdx.x;
  const int idx = (raw & 7) * 56 + (raw >> 3);   // 448/8 = 56, bijective
  if (idx < 384) {
    gemm_body<float>(Ab, WopT, out, 768, 2048, 1024, 0, 768, 0, 2048,
                     (idx / 16) * 128, (idx % 16) * 128, As, Bs, tid);
  } else {
    int j = idx - 384;
    gemm_body<float>(Ab, WoeT, out + (size_t)4 * 768 * 2048, 256, 2048, 1024, 768, 256, 0, 1024,
                     (j / 8) * 128, (j % 8) * 128, As, Bs, tid);
  }
}

// ======================= RoPE (in place, bf16 QKV) + V-transpose, merged =======================
// blocks 0..2047: RoPE, ONE thread per (b,l,j) computing sincos ONCE and applying it to all
// 9 heads (was 9x redundant transcendentals). blocks 2048..3071: V cols -> Vt tile-major.
__global__ __launch_bounds__(256) void rope_trv_kernel(
    __bf16* __restrict__ x, const int* __restrict__ pos, __bf16* __restrict__ Vt)
{
  __shared__ __bf16 t[32][33];
  const int bid = blockIdx.x, tid = threadIdx.x;
  if (bid < 2048) {
    int idx = bid * 256 + tid;   // 4*1024*128
    int j = idx & 127;
    int bl = idx >> 7;
    int b = bl >> 10;
    int l = bl & (L_TOT - 1);
    float p = (float)pos[b * L_TOT + l];
    float f = p * expf(-(float)j * (9.210340371976184f / 128.f));
    float s, c;
    sincosf(f, &s, &c);
    size_t rowb = (size_t)bl * LDQKV;
#pragma unroll
    for (int hh = 0; hh < 9; ++hh) {
      size_t base = rowb + (hh < 8 ? hh * HD : 2048);
      float x1 = (float)x[base + j], x2 = (float)x[base + 128 + j];
      x[base + j]       = (__bf16)(x1 * c - x2 * s);
      x[base + 128 + j] = (__bf16)(x2 * c + x1 * s);
    }
  } else {
    const int j = bid - 2048;            // 0..1023 : (b, l-tile, d-tile)
    const int b = j >> 8;
    const int d0 = (j & 7) * 32, l0 = ((j >> 3) & 31) * 32;
    const int tx = tid & 31, ty = tid >> 5;
#pragma unroll
    for (int r = 0; r < 32; r += 8)
      t[ty + r][tx] = x[(size_t)(b * L_TOT + l0 + ty + r) * LDQKV + 2304 + d0 + tx];
    __syncthreads();
#pragma unroll
    for (int r = 0; r < 32; r += 8)
      Vt[((size_t)(b * 32 + (l0 >> 5)) * 256 + (d0 + ty + r)) * 32 + tx] = t[tx][ty + r];
  }
}

// ======================= MFMA flash attention (double-buffered, bf16 QKV) =======================
// R7 structure unchanged: static-max softmax, LDS-staged f16 mask, tile-major Vt staging,
// deferred sum-reduce.
__global__ __launch_bounds__(256) void attn_mfma_kernel(
    const __bf16* __restrict__ QKV, const __bf16* __restrict__ Vt,
    const _Float16* __restrict__ maskh, __bf16* __restrict__ O)
{
  const int tid  = threadIdx.x;
  const int wave = tid >> 6, lane = tid & 63;
  const int m    = lane & 15, quad = lane >> 4;
  const int h = blockIdx.y, b = blockIdx.z;
  const int q0 = blockIdx.x * 64 + wave * 16;

  __shared__ __align__(16) __bf16 Ks[2][32 * 256];   // [buf][key][dim], group rotated by key
  __shared__ __align__(16) __bf16 Vs[2][256 * 32];   // [buf][dim][key], group rotated by (d>>1)&3
  __shared__ __align__(16) __bf16 Ps[4][16][40];
  __shared__ __align__(16) _Float16 Ms[4][2][16][32]; // [wave][buf][qrow][key]

  // ---- Q A-fragments: direct bf16 16B loads. A[m][k=kf*32+quad*8+j] ----
  bf16x8 qf[8];
  {
    const __bf16* qrow = QKV + (size_t)(b * L_TOT + q0 + m) * LDQKV + h * HD + quad * 8;
#pragma unroll
    for (int f = 0; f < 8; ++f) qf[f] = *(const bf16x8*)(qrow + f * 32);
  }

  const int krow_l = lane >> 5;
  const int vd_l   = lane >> 2;
  const int vg_l   = lane & 3;

  size_t ksrc[4], vsrc[4];
#pragma unroll
  for (int i = 0; i < 4; ++i) {
    int c = wave * 4 + i;
    int r = 2 * c + krow_l;
    int colg = ((lane & 31) - r) & 31;
    ksrc[i] = (size_t)(b * L_TOT + r) * LDQKV + 2048 + colg * 8;   // K cols of QKV
    int d = c * 16 + vd_l;
    int gg = (vg_l - ((d >> 1) & 3)) & 3;
    vsrc[i] = (size_t)b * 262144 + d * 32 + gg * 8;  // VT[b][0][d][gg*8]
  }

  // mask staging: lane covers row=lane>>2 (16 q-rows), seg=lane&3 (4 x 8 keys)
  const _Float16* mh = maskh + (size_t)(b * L_TOT + q0 + (lane >> 2)) * L_TOT + (lane & 3) * 8;
  _Float16* msw = &Ms[wave][0][0][0];

  f32x4 Oacc[16];
#pragma unroll
  for (int i = 0; i < 16; ++i) Oacc[i] = (f32x4){0.f, 0.f, 0.f, 0.f};
  float lrow[4] = {0.f, 0.f, 0.f, 0.f};

#pragma unroll
  for (int i = 0; i < 4; ++i) {
    int c = wave * 4 + i;
    gld_lds16(QKV + ksrc[i], &Ks[0][c * 512]);
    gld_lds16(Vt + vsrc[i], &Vs[0][c * 512]);
  }
  gld_lds16((const __bf16*)mh, (__bf16*)msw);

  for (int it = 0; it < 32; ++it) {
    const int kt = it * 32;
    const int buf = it & 1;
    __syncthreads();

    if (it + 1 < 32) {
#pragma unroll
      for (int i = 0; i < 4; ++i) {
        int c = wave * 4 + i;
        gld_lds16(QKV + ksrc[i] + (size_t)(kt + 32) * LDQKV, &Ks[buf ^ 1][c * 512]);
        gld_lds16(Vt + vsrc[i] + (size_t)(it + 1) * 8192, &Vs[buf ^ 1][c * 512]);
      }
      gld_lds16((const __bf16*)(mh + kt + 32), (__bf16*)(msw + (buf ^ 1) * 512));
    }

    f32x4 S[2];
#pragma unroll
    for (int nb = 0; nb < 2; ++nb) {
      int row = nb * 16 + m;
      f32x4 se = (f32x4){0.f, 0.f, 0.f, 0.f};
      f32x4 so = (f32x4){0.f, 0.f, 0.f, 0.f};
#pragma unroll
      for (int kf = 0; kf < 8; ++kf) {
        bf16x8 kf8 = *(const bf16x8*)(&Ks[buf][0] + row * 256 + (((kf << 2) + quad + row) & 31) * 8);
        if (kf & 1) so = __builtin_amdgcn_mfma_f32_16x16x32_bf16(qf[kf], kf8, so, 0, 0, 0);
        else        se = __builtin_amdgcn_mfma_f32_16x16x32_bf16(qf[kf], kf8, se, 0, 0, 0);
      }
      S[nb] = se + so;
    }

    // static-max softmax: p = exp(S*scale + mask - 20); per-lane partial sums only.
#pragma unroll
    for (int nb = 0; nb < 2; ++nb)
#pragma unroll
      for (int r = 0; r < 4; ++r) {
        float mval = (float)Ms[wave][buf][quad * 4 + r][nb * 16 + m];
        float p = __expf(S[nb][r] * 0.0625f + mval - 20.f);
        lrow[r] += p;
        Ps[wave][quad * 4 + r][nb * 16 + m] = (__bf16)p;
      }

    bf16x8 pf = *(const bf16x8*)&Ps[wave][m][quad * 8];
#pragma unroll
    for (int nb2 = 0; nb2 < 16; ++nb2) {
      int d = nb2 * 16 + m;
      bf16x8 vfrag = *(const bf16x8*)(&Vs[buf][0] + d * 32 + ((quad + ((d >> 1) & 3)) & 3) * 8);
      Oacc[nb2] = __builtin_amdgcn_mfma_f32_16x16x32_bf16(pf, vfrag, Oacc[nb2], 0, 0, 0);
    }
  }

  // one-time sum reduce over the 16 key-lanes (was per-iteration)
#pragma unroll
  for (int off = 1; off < 16; off <<= 1)
#pragma unroll
    for (int r = 0; r < 4; ++r)
      lrow[r] += __shfl_xor(lrow[r], off, 64);

  float invl[4];
#pragma unroll
  for (int r = 0; r < 4; ++r) invl[r] = 1.f / lrow[r];
  __bf16* orow = O + (size_t)(b * L_TOT + q0 + quad * 4) * 2048 + h * HD + m;
#pragma unroll
  for (int nb2 = 0; nb2 < 16; ++nb2)
#pragma unroll
    for (int r = 0; r < 4; ++r)
      orow[(size_t)r * 2048 + nb2 * 16] = (__bf16)(Oacc[nb2][r] * invl[r]);
}

extern "C" void kernel_launch(void* const* d_in, const int* in_sizes, int n_in,
                              void* d_out, int out_size, void* d_ws, size_t ws_size,
                              hipStream_t stream) {
  const float* pali = (const float*)d_in[0];
  const float* expe = (const float*)d_in[1];
  const int*   pos  = (const int*)d_in[2];
  const float* mask = (const float*)d_in[3];
  const float* wq_p = (const float*)d_in[5];
  const float* wk_p = (const float*)d_in[6];
  const float* wv_p = (const float*)d_in[7];
  const float* wo_p = (const float*)d_in[8];
  const float* wq_e = (const float*)d_in[9];
  const float* wk_e = (const float*)d_in[10];
  const float* wv_e = (const float*)d_in[11];
  const float* wo_e = (const float*)d_in[12];
  float* out = (float*)d_out;

  // Workspace (all bf16 except noted)
  __bf16* QKV    = (__bf16*)d_ws;                      // 4*1024*2560
  __bf16* Ab     = QKV + (size_t)4 * 1024 * 2560;      // 4*1024*2048
  __bf16* palib  = Ab + (size_t)4 * 1024 * 2048;       // 4*768*2048
  __bf16* expeb  = palib + (size_t)4 * 768 * 2048;     // 4*256*1024
  __bf16* Vt     = expeb + (size_t)4 * 256 * 1024;     // 4*256*1024 (tile-major: [b][32][256][32])
  __bf16* WqkvpT = Vt + (size_t)4 * 256 * 1024;        // 2560*2048
  __bf16* WqkveT = WqkvpT + (size_t)2560 * 2048;       // 2560*1024
  __bf16* WopT   = WqkveT + (size_t)2560 * 1024;       // 2048*2048
  __bf16* WoeT   = WopT + (size_t)2048 * 2048;         // 1024*2048
  _Float16* maskh = (_Float16*)(WoeT + (size_t)2048 * 1024); // 4*1024*1024 f16

  dim3 blk(256);
  prep_kernel<<<25088, blk, 0, stream>>>(pali, expe, wq_p, wk_p, wv_p, wq_e, wk_e, wv_e,
                                         wo_p, wo_e, mask, palib, expeb, WqkvpT, WqkveT,
                                         WopT, WoeT, maskh);
  gemm_qkv_kernel<<<640, blk, 0, stream>>>(palib, expeb, WqkvpT, WqkveT, QKV);
  rope_trv_kernel<<<2048 + 1024, blk, 0, stream>>>(QKV, pos, Vt);
  attn_mfma_kernel<<<dim3(16, 8, 4), blk, 0, stream>>>(QKV, Vt, maskh, Ab);
  gemm_out_kernel<<<448, blk, 0, stream>>>(Ab, WopT, WoeT, out);
}

// Round 9
// 351.441 us; speedup vs baseline: 1.0446x; 1.0446x over previous
//
#include <hip/hip_runtime.h>
#include <hip/hip_bf16.h>
#include <math.h>

#define L_TOT 1024
#define HD 256
#define LDQKV 2560   // fused Q|K|V row width (bf16): 2048 Q + 256 K + 256 V

typedef __bf16 bf16x8 __attribute__((ext_vector_type(8)));
typedef __bf16 bf16x4 __attribute__((ext_vector_type(4)));
typedef _Float16 f16x4 __attribute__((ext_vector_type(4)));
typedef float f32x4 __attribute__((ext_vector_type(4)));

__device__ __forceinline__ void gld_lds16(const __bf16* g, __bf16* l) {
  __builtin_amdgcn_global_load_lds(
      (const __attribute__((address_space(1))) void*)g,
      (__attribute__((address_space(3))) void*)l, 16, 0, 0);
}

// ======================= PREP: all weight transposes + activation cvts =======================
__device__ __forceinline__ void do_cvt(const float* __restrict__ in, __bf16* __restrict__ out,
                                       int i) {
  float4 v = ((const float4*)in)[i];
  bf16x4 o;
  o[0] = (__bf16)v.x; o[1] = (__bf16)v.y; o[2] = (__bf16)v.z; o[3] = (__bf16)v.w;
  ((bf16x4*)out)[i] = o;
}

__device__ __forceinline__ void do_cvt_h(const float* __restrict__ in, _Float16* __restrict__ out,
                                         int i) {
  float4 v = ((const float4*)in)[i];
  f16x4 o;
  o[0] = (_Float16)v.x; o[1] = (_Float16)v.y; o[2] = (_Float16)v.z; o[3] = (_Float16)v.w;
  ((f16x4*)out)[i] = o;
}

__device__ __forceinline__ void do_transpose(const float* __restrict__ W, __bf16* __restrict__ Wt,
                                             int K, int N, int rem, int tid, float (*t)[33]) {
  const int tiles_x = N >> 5;
  const int n0 = (rem % tiles_x) * 32, k0 = (rem / tiles_x) * 32;
  const int tx = tid & 31, ty = tid >> 5;  // ty 0..7
#pragma unroll
  for (int r = 0; r < 32; r += 8)
    t[ty + r][tx] = W[(size_t)(k0 + ty + r) * N + n0 + tx];
  __syncthreads();
#pragma unroll
  for (int r = 0; r < 32; r += 8)
    Wt[(size_t)(n0 + ty + r) * K + k0 + tx] = (__bf16)t[tx][ty + r];
}

// segments (cumulative blocks): cvt_pali 6144 | cvt_expe 1024 | wq_p 4096 | wk_p 512 |
// wv_p 512 | wq_e 2048 | wk_e 256 | wv_e 256 | wo_p 4096 | wo_e 2048 | mask_cvt 4096 => 25088
__global__ __launch_bounds__(256) void prep_kernel(
    const float* __restrict__ pali, const float* __restrict__ expe,
    const float* __restrict__ wq_p, const float* __restrict__ wk_p, const float* __restrict__ wv_p,
    const float* __restrict__ wq_e, const float* __restrict__ wk_e, const float* __restrict__ wv_e,
    const float* __restrict__ wo_p, const float* __restrict__ wo_e,
    const float* __restrict__ mask,
    __bf16* __restrict__ palib, __bf16* __restrict__ expeb,
    __bf16* __restrict__ WqkvpT, __bf16* __restrict__ WqkveT,
    __bf16* __restrict__ WopT, __bf16* __restrict__ WoeT,
    _Float16* __restrict__ maskh)
{
  __shared__ float t[32][33];
  const int bid = blockIdx.x, tid = threadIdx.x;
  if      (bid <  6144) do_cvt(pali, palib, bid * 256 + tid);
  else if (bid <  7168) do_cvt(expe, expeb, (bid - 6144) * 256 + tid);
  else if (bid < 11264) do_transpose(wq_p, WqkvpT,                       2048, 2048, bid - 7168,  tid, t);
  else if (bid < 11776) do_transpose(wk_p, WqkvpT + (size_t)2048 * 2048, 2048,  256, bid - 11264, tid, t);
  else if (bid < 12288) do_transpose(wv_p, WqkvpT + (size_t)2304 * 2048, 2048,  256, bid - 11776, tid, t);
  else if (bid < 14336) do_transpose(wq_e, WqkveT,                       1024, 2048, bid - 12288, tid, t);
  else if (bid < 14592) do_transpose(wk_e, WqkveT + (size_t)2048 * 1024, 1024,  256, bid - 14336, tid, t);
  else if (bid < 14848) do_transpose(wv_e, WqkveT + (size_t)2304 * 1024, 1024,  256, bid - 14592, tid, t);
  else if (bid < 18944) do_transpose(wo_p, WopT,                         2048, 2048, bid - 14848, tid, t);
  else if (bid < 20992) do_transpose(wo_e, WoeT,                         2048, 1024, bid - 18944, tid, t);
  else                  do_cvt_h(mask, maskh, (bid - 20992) * 256 + tid);
}

// ======================= bf16 MFMA GEMM body (m97 structure) =======================
template <typename OutT>
__device__ __forceinline__ void gemm_body(
    const __bf16* __restrict__ A, const __bf16* __restrict__ Wt, OutT* __restrict__ C,
    int La, int K, int A_Ls, int A_off, int C_Ls, int C_off, int ldc,
    int m0, int n0, __bf16* As, __bf16* Bs, int tid)
{
  const int wave = tid >> 6, lane = tid & 63;
  const int lrow = lane >> 2;
  const int k8   = lane & 3;

  const __bf16 *ag0, *ag1;
  {
    int m_a0 = m0 + wave * 16 + lrow;
    int m_a1 = m_a0 + 64;
    int b0 = m_a0 / La, b1 = m_a1 / La;
    ag0 = A + (size_t)(b0 * A_Ls + A_off + m_a0 - b0 * La) * K + k8 * 8;
    ag1 = A + (size_t)(b1 * A_Ls + A_off + m_a1 - b1 * La) * K + k8 * 8;
  }
  const __bf16* bg0 = Wt + (size_t)(n0 + wave * 16 + lrow) * K + k8 * 8;
  const __bf16* bg1 = bg0 + (size_t)64 * K;
  __bf16* al0 = As + wave * 512;
  __bf16* al1 = As + (4 + wave) * 512;
  __bf16* bl0 = Bs + wave * 512;
  __bf16* bl1 = Bs + (4 + wave) * 512;

  const int wm = (wave & 1) * 64, wn = (wave >> 1) * 64;
  const int fr = lane & 15, quad = lane >> 4;

  f32x4 acc[4][4];
#pragma unroll
  for (int i = 0; i < 4; ++i)
#pragma unroll
    for (int j = 0; j < 4; ++j) acc[i][j] = (f32x4){0.f, 0.f, 0.f, 0.f};

  for (int kk = 0; kk < K; kk += 32) {
    gld_lds16(ag0 + kk, al0);
    gld_lds16(ag1 + kk, al1);
    gld_lds16(bg0 + kk, bl0);
    gld_lds16(bg1 + kk, bl1);
    __syncthreads();
    bf16x8 af[4], bfr[4];
#pragma unroll
    for (int mt = 0; mt < 4; ++mt)
      af[mt] = *(const bf16x8*)(As + (wm + mt * 16 + fr) * 32 + quad * 8);
#pragma unroll
    for (int nt = 0; nt < 4; ++nt)
      bfr[nt] = *(const bf16x8*)(Bs + (wn + nt * 16 + fr) * 32 + quad * 8);
#pragma unroll
    for (int mt = 0; mt < 4; ++mt)
#pragma unroll
      for (int nt = 0; nt < 4; ++nt)
        acc[mt][nt] = __builtin_amdgcn_mfma_f32_16x16x32_bf16(af[mt], bfr[nt], acc[mt][nt], 0, 0, 0);
    __syncthreads();
  }

#pragma unroll
  for (int mt = 0; mt < 4; ++mt) {
#pragma unroll
    for (int r = 0; r < 4; ++r) {
      int m = m0 + wm + mt * 16 + quad * 4 + r;
      int b = m / La;
      OutT* crow = C + (size_t)(b * C_Ls + C_off + m - b * La) * ldc + n0 + wn + fr;
#pragma unroll
      for (int nt = 0; nt < 4; ++nt) crow[nt * 16] = (OutT)acc[mt][nt][r];
    }
  }
}

// Merged QKV projection: blocks 0..479 pali (24x20 tiles), 480..639 expert (8x20). bf16 out.
// (R8's XCD-chunked swizzle REVERTED: it forced each XCD to stream all of B through its
//  4MB L2 -> thrash; natural round-robin interleave is faster here.)
__global__ __launch_bounds__(256) void gemm_qkv_kernel(
    const __bf16* __restrict__ palib, const __bf16* __restrict__ expeb,
    const __bf16* __restrict__ WqkvpT, const __bf16* __restrict__ WqkveT,
    __bf16* __restrict__ QKV)
{
  __shared__ __bf16 As[128 * 32];
  __shared__ __bf16 Bs[128 * 32];
  const int idx = blockIdx.x, tid = threadIdx.x;
  if (idx < 480) {
    gemm_body<__bf16>(palib, WqkvpT, QKV, 768, 2048, 768, 0, L_TOT, 0, LDQKV,
                      (idx / 20) * 128, (idx % 20) * 128, As, Bs, tid);
  } else {
    int j = idx - 480;
    gemm_body<__bf16>(expeb, WqkveT, QKV, 256, 1024, 256, 0, L_TOT, 768, LDQKV,
                      (j / 20) * 128, (j % 20) * 128, As, Bs, tid);
  }
}

// Merged output projection: blocks 0..383 pali (24x16), 384..447 expert (8x8). f32 out.
__global__ __launch_bounds__(256) void gemm_out_kernel(
    const __bf16* __restrict__ Ab, const __bf16* __restrict__ WopT,
    const __bf16* __restrict__ WoeT, float* __restrict__ out)
{
  __shared__ __bf16 As[128 * 32];
  __shared__ __bf16 Bs[128 * 32];
  const int idx = blockIdx.x, tid = threadIdx.x;
  if (idx < 384) {
    gemm_body<float>(Ab, WopT, out, 768, 2048, 1024, 0, 768, 0, 2048,
                     (idx / 16) * 128, (idx % 16) * 128, As, Bs, tid);
  } else {
    int j = idx - 384;
    gemm_body<float>(Ab, WoeT, out + (size_t)4 * 768 * 2048, 256, 2048, 1024, 768, 256, 0, 1024,
                     (j / 8) * 128, (j % 8) * 128, As, Bs, tid);
  }
}

// ======================= RoPE (in place, bf16 QKV) + V-transpose, merged =======================
// blocks 0..2047: RoPE, ONE thread per (b,l,j) computing sincos ONCE and applying it to all
// 9 heads (kept from R8: ~14us win). blocks 2048..3071: V cols -> Vt tile-major.
__global__ __launch_bounds__(256) void rope_trv_kernel(
    __bf16* __restrict__ x, const int* __restrict__ pos, __bf16* __restrict__ Vt)
{
  __shared__ __bf16 t[32][33];
  const int bid = blockIdx.x, tid = threadIdx.x;
  if (bid < 2048) {
    int idx = bid * 256 + tid;   // 4*1024*128
    int j = idx & 127;
    int bl = idx >> 7;
    int b = bl >> 10;
    int l = bl & (L_TOT - 1);
    float p = (float)pos[b * L_TOT + l];
    float f = p * expf(-(float)j * (9.210340371976184f / 128.f));
    float s, c;
    sincosf(f, &s, &c);
    size_t rowb = (size_t)bl * LDQKV;
#pragma unroll
    for (int hh = 0; hh < 9; ++hh) {
      size_t base = rowb + (hh < 8 ? hh * HD : 2048);
      float x1 = (float)x[base + j], x2 = (float)x[base + 128 + j];
      x[base + j]       = (__bf16)(x1 * c - x2 * s);
      x[base + 128 + j] = (__bf16)(x2 * c + x1 * s);
    }
  } else {
    const int j = bid - 2048;            // 0..1023 : (b, l-tile, d-tile)
    const int b = j >> 8;
    const int d0 = (j & 7) * 32, l0 = ((j >> 3) & 31) * 32;
    const int tx = tid & 31, ty = tid >> 5;
#pragma unroll
    for (int r = 0; r < 32; r += 8)
      t[ty + r][tx] = x[(size_t)(b * L_TOT + l0 + ty + r) * LDQKV + 2304 + d0 + tx];
    __syncthreads();
#pragma unroll
    for (int r = 0; r < 32; r += 8)
      Vt[((size_t)(b * 32 + (l0 >> 5)) * 256 + (d0 + ty + r)) * 32 + tx] = t[tx][ty + r];
  }
}

// ======================= MFMA flash attention (double-buffered, bf16 QKV) =======================
// R7 structure unchanged: static-max softmax, LDS-staged f16 mask, tile-major Vt staging,
// deferred sum-reduce.
__global__ __launch_bounds__(256) void attn_mfma_kernel(
    const __bf16* __restrict__ QKV, const __bf16* __restrict__ Vt,
    const _Float16* __restrict__ maskh, __bf16* __restrict__ O)
{
  const int tid  = threadIdx.x;
  const int wave = tid >> 6, lane = tid & 63;
  const int m    = lane & 15, quad = lane >> 4;
  const int h = blockIdx.y, b = blockIdx.z;
  const int q0 = blockIdx.x * 64 + wave * 16;

  __shared__ __align__(16) __bf16 Ks[2][32 * 256];   // [buf][key][dim], group rotated by key
  __shared__ __align__(16) __bf16 Vs[2][256 * 32];   // [buf][dim][key], group rotated by (d>>1)&3
  __shared__ __align__(16) __bf16 Ps[4][16][40];
  __shared__ __align__(16) _Float16 Ms[4][2][16][32]; // [wave][buf][qrow][key]

  // ---- Q A-fragments: direct bf16 16B loads. A[m][k=kf*32+quad*8+j] ----
  bf16x8 qf[8];
  {
    const __bf16* qrow = QKV + (size_t)(b * L_TOT + q0 + m) * LDQKV + h * HD + quad * 8;
#pragma unroll
    for (int f = 0; f < 8; ++f) qf[f] = *(const bf16x8*)(qrow + f * 32);
  }

  const int krow_l = lane >> 5;
  const int vd_l   = lane >> 2;
  const int vg_l   = lane & 3;

  size_t ksrc[4], vsrc[4];
#pragma unroll
  for (int i = 0; i < 4; ++i) {
    int c = wave * 4 + i;
    int r = 2 * c + krow_l;
    int colg = ((lane & 31) - r) & 31;
    ksrc[i] = (size_t)(b * L_TOT + r) * LDQKV + 2048 + colg * 8;   // K cols of QKV
    int d = c * 16 + vd_l;
    int gg = (vg_l - ((d >> 1) & 3)) & 3;
    vsrc[i] = (size_t)b * 262144 + d * 32 + gg * 8;  // VT[b][0][d][gg*8]
  }

  // mask staging: lane covers row=lane>>2 (16 q-rows), seg=lane&3 (4 x 8 keys)
  const _Float16* mh = maskh + (size_t)(b * L_TOT + q0 + (lane >> 2)) * L_TOT + (lane & 3) * 8;
  _Float16* msw = &Ms[wave][0][0][0];

  f32x4 Oacc[16];
#pragma unroll
  for (int i = 0; i < 16; ++i) Oacc[i] = (f32x4){0.f, 0.f, 0.f, 0.f};
  float lrow[4] = {0.f, 0.f, 0.f, 0.f};

#pragma unroll
  for (int i = 0; i < 4; ++i) {
    int c = wave * 4 + i;
    gld_lds16(QKV + ksrc[i], &Ks[0][c * 512]);
    gld_lds16(Vt + vsrc[i], &Vs[0][c * 512]);
  }
  gld_lds16((const __bf16*)mh, (__bf16*)msw);

  for (int it = 0; it < 32; ++it) {
    const int kt = it * 32;
    const int buf = it & 1;
    __syncthreads();

    if (it + 1 < 32) {
#pragma unroll
      for (int i = 0; i < 4; ++i) {
        int c = wave * 4 + i;
        gld_lds16(QKV + ksrc[i] + (size_t)(kt + 32) * LDQKV, &Ks[buf ^ 1][c * 512]);
        gld_lds16(Vt + vsrc[i] + (size_t)(it + 1) * 8192, &Vs[buf ^ 1][c * 512]);
      }
      gld_lds16((const __bf16*)(mh + kt + 32), (__bf16*)(msw + (buf ^ 1) * 512));
    }

    f32x4 S[2];
#pragma unroll
    for (int nb = 0; nb < 2; ++nb) {
      int row = nb * 16 + m;
      f32x4 se = (f32x4){0.f, 0.f, 0.f, 0.f};
      f32x4 so = (f32x4){0.f, 0.f, 0.f, 0.f};
#pragma unroll
      for (int kf = 0; kf < 8; ++kf) {
        bf16x8 kf8 = *(const bf16x8*)(&Ks[buf][0] + row * 256 + (((kf << 2) + quad + row) & 31) * 8);
        if (kf & 1) so = __builtin_amdgcn_mfma_f32_16x16x32_bf16(qf[kf], kf8, so, 0, 0, 0);
        else        se = __builtin_amdgcn_mfma_f32_16x16x32_bf16(qf[kf], kf8, se, 0, 0, 0);
      }
      S[nb] = se + so;
    }

    // static-max softmax: p = exp(S*scale + mask - 20); per-lane partial sums only.
#pragma unroll
    for (int nb = 0; nb < 2; ++nb)
#pragma unroll
      for (int r = 0; r < 4; ++r) {
        float mval = (float)Ms[wave][buf][quad * 4 + r][nb * 16 + m];
        float p = __expf(S[nb][r] * 0.0625f + mval - 20.f);
        lrow[r] += p;
        Ps[wave][quad * 4 + r][nb * 16 + m] = (__bf16)p;
      }

    bf16x8 pf = *(const bf16x8*)&Ps[wave][m][quad * 8];
#pragma unroll
    for (int nb2 = 0; nb2 < 16; ++nb2) {
      int d = nb2 * 16 + m;
      bf16x8 vfrag = *(const bf16x8*)(&Vs[buf][0] + d * 32 + ((quad + ((d >> 1) & 3)) & 3) * 8);
      Oacc[nb2] = __builtin_amdgcn_mfma_f32_16x16x32_bf16(pf, vfrag, Oacc[nb2], 0, 0, 0);
    }
  }

  // one-time sum reduce over the 16 key-lanes (was per-iteration)
#pragma unroll
  for (int off = 1; off < 16; off <<= 1)
#pragma unroll
    for (int r = 0; r < 4; ++r)
      lrow[r] += __shfl_xor(lrow[r], off, 64);

  float invl[4];
#pragma unroll
  for (int r = 0; r < 4; ++r) invl[r] = 1.f / lrow[r];
  __bf16* orow = O + (size_t)(b * L_TOT + q0 + quad * 4) * 2048 + h * HD + m;
#pragma unroll
  for (int nb2 = 0; nb2 < 16; ++nb2)
#pragma unroll
    for (int r = 0; r < 4; ++r)
      orow[(size_t)r * 2048 + nb2 * 16] = (__bf16)(Oacc[nb2][r] * invl[r]);
}

extern "C" void kernel_launch(void* const* d_in, const int* in_sizes, int n_in,
                              void* d_out, int out_size, void* d_ws, size_t ws_size,
                              hipStream_t stream) {
  const float* pali = (const float*)d_in[0];
  const float* expe = (const float*)d_in[1];
  const int*   pos  = (const int*)d_in[2];
  const float* mask = (const float*)d_in[3];
  const float* wq_p = (const float*)d_in[5];
  const float* wk_p = (const float*)d_in[6];
  const float* wv_p = (const float*)d_in[7];
  const float* wo_p = (const float*)d_in[8];
  const float* wq_e = (const float*)d_in[9];
  const float* wk_e = (const float*)d_in[10];
  const float* wv_e = (const float*)d_in[11];
  const float* wo_e = (const float*)d_in[12];
  float* out = (float*)d_out;

  // Workspace (all bf16 except noted)
  __bf16* QKV    = (__bf16*)d_ws;                      // 4*1024*2560
  __bf16* Ab     = QKV + (size_t)4 * 1024 * 2560;      // 4*1024*2048
  __bf16* palib  = Ab + (size_t)4 * 1024 * 2048;       // 4*768*2048
  __bf16* expeb  = palib + (size_t)4 * 768 * 2048;     // 4*256*1024
  __bf16* Vt     = expeb + (size_t)4 * 256 * 1024;     // 4*256*1024 (tile-major: [b][32][256][32])
  __bf16* WqkvpT = Vt + (size_t)4 * 256 * 1024;        // 2560*2048
  __bf16* WqkveT = WqkvpT + (size_t)2560 * 2048;       // 2560*1024
  __bf16* WopT   = WqkveT + (size_t)2560 * 1024;       // 2048*2048
  __bf16* WoeT   = WopT + (size_t)2048 * 2048;         // 1024*2048
  _Float16* maskh = (_Float16*)(WoeT + (size_t)2048 * 1024); // 4*1024*1024 f16

  dim3 blk(256);
  prep_kernel<<<25088, blk, 0, stream>>>(pali, expe, wq_p, wk_p, wv_p, wq_e, wk_e, wv_e,
                                         wo_p, wo_e, mask, palib, expeb, WqkvpT, WqkveT,
                                         WopT, WoeT, maskh);
  gemm_qkv_kernel<<<640, blk, 0, stream>>>(palib, expeb, WqkvpT, WqkveT, QKV);
  rope_trv_kernel<<<2048 + 1024, blk, 0, stream>>>(QKV, pos, Vt);
  attn_mfma_kernel<<<dim3(16, 8, 4), blk, 0, stream>>>(QKV, Vt, maskh, Ab);
  gemm_out_kernel<<<448, blk, 0, stream>>>(Ab, WopT, WoeT, out);
}

// Round 10
// 320.001 us; speedup vs baseline: 1.1472x; 1.0983x over previous
//
#include <hip/hip_runtime.h>
#include <hip/hip_bf16.h>
#include <math.h>

#define L_TOT 1024
#define HD 256
#define LDQKV 2560   // fused Q|K|V row width (bf16): 2048 Q + 256 K + 256 V

typedef __bf16 bf16x8 __attribute__((ext_vector_type(8)));
typedef __bf16 bf16x4 __attribute__((ext_vector_type(4)));
typedef _Float16 f16x4 __attribute__((ext_vector_type(4)));
typedef float f32x4 __attribute__((ext_vector_type(4)));

__device__ __forceinline__ void gld_lds16(const __bf16* g, __bf16* l) {
  __builtin_amdgcn_global_load_lds(
      (const __attribute__((address_space(1))) void*)g,
      (__attribute__((address_space(3))) void*)l, 16, 0, 0);
}

// ======================= PREP: all weight transposes + activation cvts =======================
__device__ __forceinline__ void do_cvt(const float* __restrict__ in, __bf16* __restrict__ out,
                                       int i) {
  float4 v = ((const float4*)in)[i];
  bf16x4 o;
  o[0] = (__bf16)v.x; o[1] = (__bf16)v.y; o[2] = (__bf16)v.z; o[3] = (__bf16)v.w;
  ((bf16x4*)out)[i] = o;
}

__device__ __forceinline__ void do_cvt_h(const float* __restrict__ in, _Float16* __restrict__ out,
                                         int i) {
  float4 v = ((const float4*)in)[i];
  f16x4 o;
  o[0] = (_Float16)v.x; o[1] = (_Float16)v.y; o[2] = (_Float16)v.z; o[3] = (_Float16)v.w;
  ((f16x4*)out)[i] = o;
}

__device__ __forceinline__ void do_transpose(const float* __restrict__ W, __bf16* __restrict__ Wt,
                                             int K, int N, int rem, int tid, float (*t)[33]) {
  const int tiles_x = N >> 5;
  const int n0 = (rem % tiles_x) * 32, k0 = (rem / tiles_x) * 32;
  const int tx = tid & 31, ty = tid >> 5;  // ty 0..7
#pragma unroll
  for (int r = 0; r < 32; r += 8)
    t[ty + r][tx] = W[(size_t)(k0 + ty + r) * N + n0 + tx];
  __syncthreads();
#pragma unroll
  for (int r = 0; r < 32; r += 8)
    Wt[(size_t)(n0 + ty + r) * K + k0 + tx] = (__bf16)t[tx][ty + r];
}

// segments (cumulative blocks): cvt_pali 6144 | cvt_expe 1024 | wq_p 4096 | wk_p 512 |
// wv_p 512 | wq_e 2048 | wk_e 256 | wv_e 256 | wo_p 4096 | wo_e 2048 | mask_cvt 4096 => 25088
__global__ __launch_bounds__(256) void prep_kernel(
    const float* __restrict__ pali, const float* __restrict__ expe,
    const float* __restrict__ wq_p, const float* __restrict__ wk_p, const float* __restrict__ wv_p,
    const float* __restrict__ wq_e, const float* __restrict__ wk_e, const float* __restrict__ wv_e,
    const float* __restrict__ wo_p, const float* __restrict__ wo_e,
    const float* __restrict__ mask,
    __bf16* __restrict__ palib, __bf16* __restrict__ expeb,
    __bf16* __restrict__ WqkvpT, __bf16* __restrict__ WqkveT,
    __bf16* __restrict__ WopT, __bf16* __restrict__ WoeT,
    _Float16* __restrict__ maskh)
{
  __shared__ float t[32][33];
  const int bid = blockIdx.x, tid = threadIdx.x;
  if      (bid <  6144) do_cvt(pali, palib, bid * 256 + tid);
  else if (bid <  7168) do_cvt(expe, expeb, (bid - 6144) * 256 + tid);
  else if (bid < 11264) do_transpose(wq_p, WqkvpT,                       2048, 2048, bid - 7168,  tid, t);
  else if (bid < 11776) do_transpose(wk_p, WqkvpT + (size_t)2048 * 2048, 2048,  256, bid - 11264, tid, t);
  else if (bid < 12288) do_transpose(wv_p, WqkvpT + (size_t)2304 * 2048, 2048,  256, bid - 11776, tid, t);
  else if (bid < 14336) do_transpose(wq_e, WqkveT,                       1024, 2048, bid - 12288, tid, t);
  else if (bid < 14592) do_transpose(wk_e, WqkveT + (size_t)2048 * 1024, 1024,  256, bid - 14336, tid, t);
  else if (bid < 14848) do_transpose(wv_e, WqkveT + (size_t)2304 * 1024, 1024,  256, bid - 14592, tid, t);
  else if (bid < 18944) do_transpose(wo_p, WopT,                         2048, 2048, bid - 14848, tid, t);
  else if (bid < 20992) do_transpose(wo_e, WoeT,                         2048, 1024, bid - 18944, tid, t);
  else                  do_cvt_h(mask, maskh, (bid - 20992) * 256 + tid);
}

// ======================= bf16 MFMA GEMM body (m97 structure, BK=64) =======================
// Two 32-K sub-steps per barrier pair: one staging round fills both LDS half-tiles,
// then both halves are consumed back-to-back. Halves the per-K barrier/vmcnt(0)
// drain count vs BK=32. LDS 2x (16KB->32KB): still 5 blocks/CU capacity (grid-limited).
template <typename OutT>
__device__ __forceinline__ void gemm_body(
    const __bf16* __restrict__ A, const __bf16* __restrict__ Wt, OutT* __restrict__ C,
    int La, int K, int A_Ls, int A_off, int C_Ls, int C_off, int ldc,
    int m0, int n0, __bf16* As, __bf16* Bs, int tid)
{
  const int wave = tid >> 6, lane = tid & 63;
  const int lrow = lane >> 2;
  const int k8   = lane & 3;

  const __bf16 *ag0, *ag1;
  {
    int m_a0 = m0 + wave * 16 + lrow;
    int m_a1 = m_a0 + 64;
    int b0 = m_a0 / La, b1 = m_a1 / La;
    ag0 = A + (size_t)(b0 * A_Ls + A_off + m_a0 - b0 * La) * K + k8 * 8;
    ag1 = A + (size_t)(b1 * A_Ls + A_off + m_a1 - b1 * La) * K + k8 * 8;
  }
  const __bf16* bg0 = Wt + (size_t)(n0 + wave * 16 + lrow) * K + k8 * 8;
  const __bf16* bg1 = bg0 + (size_t)64 * K;
  // LDS half-tile layout: [half][128 rows][32 cols]; half stride = 4096 elems (8KB)
  __bf16* al0 = As + wave * 512;
  __bf16* al1 = As + (4 + wave) * 512;
  __bf16* bl0 = Bs + wave * 512;
  __bf16* bl1 = Bs + (4 + wave) * 512;

  const int wm = (wave & 1) * 64, wn = (wave >> 1) * 64;
  const int fr = lane & 15, quad = lane >> 4;

  f32x4 acc[4][4];
#pragma unroll
  for (int i = 0; i < 4; ++i)
#pragma unroll
    for (int j = 0; j < 4; ++j) acc[i][j] = (f32x4){0.f, 0.f, 0.f, 0.f};

  for (int kk = 0; kk < K; kk += 64) {
    gld_lds16(ag0 + kk,      al0);
    gld_lds16(ag0 + kk + 32, al0 + 4096);
    gld_lds16(ag1 + kk,      al1);
    gld_lds16(ag1 + kk + 32, al1 + 4096);
    gld_lds16(bg0 + kk,      bl0);
    gld_lds16(bg0 + kk + 32, bl0 + 4096);
    gld_lds16(bg1 + kk,      bl1);
    gld_lds16(bg1 + kk + 32, bl1 + 4096);
    __syncthreads();
#pragma unroll
    for (int h = 0; h < 2; ++h) {
      const __bf16* Ah = As + h * 4096;
      const __bf16* Bh = Bs + h * 4096;
      bf16x8 af[4], bfr[4];
#pragma unroll
      for (int mt = 0; mt < 4; ++mt)
        af[mt] = *(const bf16x8*)(Ah + (wm + mt * 16 + fr) * 32 + quad * 8);
#pragma unroll
      for (int nt = 0; nt < 4; ++nt)
        bfr[nt] = *(const bf16x8*)(Bh + (wn + nt * 16 + fr) * 32 + quad * 8);
#pragma unroll
      for (int mt = 0; mt < 4; ++mt)
#pragma unroll
        for (int nt = 0; nt < 4; ++nt)
          acc[mt][nt] = __builtin_amdgcn_mfma_f32_16x16x32_bf16(af[mt], bfr[nt], acc[mt][nt], 0, 0, 0);
    }
    __syncthreads();
  }

#pragma unroll
  for (int mt = 0; mt < 4; ++mt) {
#pragma unroll
    for (int r = 0; r < 4; ++r) {
      int m = m0 + wm + mt * 16 + quad * 4 + r;
      int b = m / La;
      OutT* crow = C + (size_t)(b * C_Ls + C_off + m - b * La) * ldc + n0 + wn + fr;
#pragma unroll
      for (int nt = 0; nt < 4; ++nt) crow[nt * 16] = (OutT)acc[mt][nt][r];
    }
  }
}

// Merged QKV projection: blocks 0..479 pali (24x20 tiles), 480..639 expert (8x20). bf16 out.
__global__ __launch_bounds__(256) void gemm_qkv_kernel(
    const __bf16* __restrict__ palib, const __bf16* __restrict__ expeb,
    const __bf16* __restrict__ WqkvpT, const __bf16* __restrict__ WqkveT,
    __bf16* __restrict__ QKV)
{
  __shared__ __bf16 As[2 * 128 * 32];
  __shared__ __bf16 Bs[2 * 128 * 32];
  const int idx = blockIdx.x, tid = threadIdx.x;
  if (idx < 480) {
    gemm_body<__bf16>(palib, WqkvpT, QKV, 768, 2048, 768, 0, L_TOT, 0, LDQKV,
                      (idx / 20) * 128, (idx % 20) * 128, As, Bs, tid);
  } else {
    int j = idx - 480;
    gemm_body<__bf16>(expeb, WqkveT, QKV, 256, 1024, 256, 0, L_TOT, 768, LDQKV,
                      (j / 20) * 128, (j % 20) * 128, As, Bs, tid);
  }
}

// Merged output projection: blocks 0..383 pali (24x16), 384..447 expert (8x8). f32 out.
__global__ __launch_bounds__(256) void gemm_out_kernel(
    const __bf16* __restrict__ Ab, const __bf16* __restrict__ WopT,
    const __bf16* __restrict__ WoeT, float* __restrict__ out)
{
  __shared__ __bf16 As[2 * 128 * 32];
  __shared__ __bf16 Bs[2 * 128 * 32];
  const int idx = blockIdx.x, tid = threadIdx.x;
  if (idx < 384) {
    gemm_body<float>(Ab, WopT, out, 768, 2048, 1024, 0, 768, 0, 2048,
                     (idx / 16) * 128, (idx % 16) * 128, As, Bs, tid);
  } else {
    int j = idx - 384;
    gemm_body<float>(Ab, WoeT, out + (size_t)4 * 768 * 2048, 256, 2048, 1024, 768, 256, 0, 1024,
                     (j / 8) * 128, (j % 8) * 128, As, Bs, tid);
  }
}

// ======================= RoPE (in place, bf16 QKV) + V-transpose, merged =======================
// blocks 0..2047: RoPE, ONE thread per (b,l,j) computing sincos ONCE and applying it to all
// 9 heads. blocks 2048..3071: V cols -> Vt tile-major.
__global__ __launch_bounds__(256) void rope_trv_kernel(
    __bf16* __restrict__ x, const int* __restrict__ pos, __bf16* __restrict__ Vt)
{
  __shared__ __bf16 t[32][33];
  const int bid = blockIdx.x, tid = threadIdx.x;
  if (bid < 2048) {
    int idx = bid * 256 + tid;   // 4*1024*128
    int j = idx & 127;
    int bl = idx >> 7;
    int b = bl >> 10;
    int l = bl & (L_TOT - 1);
    float p = (float)pos[b * L_TOT + l];
    float f = p * expf(-(float)j * (9.210340371976184f / 128.f));
    float s, c;
    sincosf(f, &s, &c);
    size_t rowb = (size_t)bl * LDQKV;
#pragma unroll
    for (int hh = 0; hh < 9; ++hh) {
      size_t base = rowb + (hh < 8 ? hh * HD : 2048);
      float x1 = (float)x[base + j], x2 = (float)x[base + 128 + j];
      x[base + j]       = (__bf16)(x1 * c - x2 * s);
      x[base + 128 + j] = (__bf16)(x2 * c + x1 * s);
    }
  } else {
    const int j = bid - 2048;            // 0..1023 : (b, l-tile, d-tile)
    const int b = j >> 8;
    const int d0 = (j & 7) * 32, l0 = ((j >> 3) & 31) * 32;
    const int tx = tid & 31, ty = tid >> 5;
#pragma unroll
    for (int r = 0; r < 32; r += 8)
      t[ty + r][tx] = x[(size_t)(b * L_TOT + l0 + ty + r) * LDQKV + 2304 + d0 + tx];
    __syncthreads();
#pragma unroll
    for (int r = 0; r < 32; r += 8)
      Vt[((size_t)(b * 32 + (l0 >> 5)) * 256 + (d0 + ty + r)) * 32 + tx] = t[tx][ty + r];
  }
}

// ======================= MFMA flash attention (double-buffered, bf16 QKV) =======================
// R7 structure unchanged: static-max softmax, LDS-staged f16 mask, tile-major Vt staging,
// deferred sum-reduce.
__global__ __launch_bounds__(256) void attn_mfma_kernel(
    const __bf16* __restrict__ QKV, const __bf16* __restrict__ Vt,
    const _Float16* __restrict__ maskh, __bf16* __restrict__ O)
{
  const int tid  = threadIdx.x;
  const int wave = tid >> 6, lane = tid & 63;
  const int m    = lane & 15, quad = lane >> 4;
  const int h = blockIdx.y, b = blockIdx.z;
  const int q0 = blockIdx.x * 64 + wave * 16;

  __shared__ __align__(16) __bf16 Ks[2][32 * 256];   // [buf][key][dim], group rotated by key
  __shared__ __align__(16) __bf16 Vs[2][256 * 32];   // [buf][dim][key], group rotated by (d>>1)&3
  __shared__ __align__(16) __bf16 Ps[4][16][40];
  __shared__ __align__(16) _Float16 Ms[4][2][16][32]; // [wave][buf][qrow][key]

  // ---- Q A-fragments: direct bf16 16B loads. A[m][k=kf*32+quad*8+j] ----
  bf16x8 qf[8];
  {
    const __bf16* qrow = QKV + (size_t)(b * L_TOT + q0 + m) * LDQKV + h * HD + quad * 8;
#pragma unroll
    for (int f = 0; f < 8; ++f) qf[f] = *(const bf16x8*)(qrow + f * 32);
  }

  const int krow_l = lane >> 5;
  const int vd_l   = lane >> 2;
  const int vg_l   = lane & 3;

  size_t ksrc[4], vsrc[4];
#pragma unroll
  for (int i = 0; i < 4; ++i) {
    int c = wave * 4 + i;
    int r = 2 * c + krow_l;
    int colg = ((lane & 31) - r) & 31;
    ksrc[i] = (size_t)(b * L_TOT + r) * LDQKV + 2048 + colg * 8;   // K cols of QKV
    int d = c * 16 + vd_l;
    int gg = (vg_l - ((d >> 1) & 3)) & 3;
    vsrc[i] = (size_t)b * 262144 + d * 32 + gg * 8;  // VT[b][0][d][gg*8]
  }

  // mask staging: lane covers row=lane>>2 (16 q-rows), seg=lane&3 (4 x 8 keys)
  const _Float16* mh = maskh + (size_t)(b * L_TOT + q0 + (lane >> 2)) * L_TOT + (lane & 3) * 8;
  _Float16* msw = &Ms[wave][0][0][0];

  f32x4 Oacc[16];
#pragma unroll
  for (int i = 0; i < 16; ++i) Oacc[i] = (f32x4){0.f, 0.f, 0.f, 0.f};
  float lrow[4] = {0.f, 0.f, 0.f, 0.f};

#pragma unroll
  for (int i = 0; i < 4; ++i) {
    int c = wave * 4 + i;
    gld_lds16(QKV + ksrc[i], &Ks[0][c * 512]);
    gld_lds16(Vt + vsrc[i], &Vs[0][c * 512]);
  }
  gld_lds16((const __bf16*)mh, (__bf16*)msw);

  for (int it = 0; it < 32; ++it) {
    const int kt = it * 32;
    const int buf = it & 1;
    __syncthreads();

    if (it + 1 < 32) {
#pragma unroll
      for (int i = 0; i < 4; ++i) {
        int c = wave * 4 + i;
        gld_lds16(QKV + ksrc[i] + (size_t)(kt + 32) * LDQKV, &Ks[buf ^ 1][c * 512]);
        gld_lds16(Vt + vsrc[i] + (size_t)(it + 1) * 8192, &Vs[buf ^ 1][c * 512]);
      }
      gld_lds16((const __bf16*)(mh + kt + 32), (__bf16*)(msw + (buf ^ 1) * 512));
    }

    f32x4 S[2];
#pragma unroll
    for (int nb = 0; nb < 2; ++nb) {
      int row = nb * 16 + m;
      f32x4 se = (f32x4){0.f, 0.f, 0.f, 0.f};
      f32x4 so = (f32x4){0.f, 0.f, 0.f, 0.f};
#pragma unroll
      for (int kf = 0; kf < 8; ++kf) {
        bf16x8 kf8 = *(const bf16x8*)(&Ks[buf][0] + row * 256 + (((kf << 2) + quad + row) & 31) * 8);
        if (kf & 1) so = __builtin_amdgcn_mfma_f32_16x16x32_bf16(qf[kf], kf8, so, 0, 0, 0);
        else        se = __builtin_amdgcn_mfma_f32_16x16x32_bf16(qf[kf], kf8, se, 0, 0, 0);
      }
      S[nb] = se + so;
    }

    // static-max softmax: p = exp(S*scale + mask - 20); per-lane partial sums only.
#pragma unroll
    for (int nb = 0; nb < 2; ++nb)
#pragma unroll
      for (int r = 0; r < 4; ++r) {
        float mval = (float)Ms[wave][buf][quad * 4 + r][nb * 16 + m];
        float p = __expf(S[nb][r] * 0.0625f + mval - 20.f);
        lrow[r] += p;
        Ps[wave][quad * 4 + r][nb * 16 + m] = (__bf16)p;
      }

    bf16x8 pf = *(const bf16x8*)&Ps[wave][m][quad * 8];
#pragma unroll
    for (int nb2 = 0; nb2 < 16; ++nb2) {
      int d = nb2 * 16 + m;
      bf16x8 vfrag = *(const bf16x8*)(&Vs[buf][0] + d * 32 + ((quad + ((d >> 1) & 3)) & 3) * 8);
      Oacc[nb2] = __builtin_amdgcn_mfma_f32_16x16x32_bf16(pf, vfrag, Oacc[nb2], 0, 0, 0);
    }
  }

  // one-time sum reduce over the 16 key-lanes (was per-iteration)
#pragma unroll
  for (int off = 1; off < 16; off <<= 1)
#pragma unroll
    for (int r = 0; r < 4; ++r)
      lrow[r] += __shfl_xor(lrow[r], off, 64);

  float invl[4];
#pragma unroll
  for (int r = 0; r < 4; ++r) invl[r] = 1.f / lrow[r];
  __bf16* orow = O + (size_t)(b * L_TOT + q0 + quad * 4) * 2048 + h * HD + m;
#pragma unroll
  for (int nb2 = 0; nb2 < 16; ++nb2)
#pragma unroll
    for (int r = 0; r < 4; ++r)
      orow[(size_t)r * 2048 + nb2 * 16] = (__bf16)(Oacc[nb2][r] * invl[r]);
}

extern "C" void kernel_launch(void* const* d_in, const int* in_sizes, int n_in,
                              void* d_out, int out_size, void* d_ws, size_t ws_size,
                              hipStream_t stream) {
  const float* pali = (const float*)d_in[0];
  const float* expe = (const float*)d_in[1];
  const int*   pos  = (const int*)d_in[2];
  const float* mask = (const float*)d_in[3];
  const float* wq_p = (const float*)d_in[5];
  const float* wk_p = (const float*)d_in[6];
  const float* wv_p = (const float*)d_in[7];
  const float* wo_p = (const float*)d_in[8];
  const float* wq_e = (const float*)d_in[9];
  const float* wk_e = (const float*)d_in[10];
  const float* wv_e = (const float*)d_in[11];
  const float* wo_e = (const float*)d_in[12];
  float* out = (float*)d_out;

  // Workspace (all bf16 except noted)
  __bf16* QKV    = (__bf16*)d_ws;                      // 4*1024*2560
  __bf16* Ab     = QKV + (size_t)4 * 1024 * 2560;      // 4*1024*2048
  __bf16* palib  = Ab + (size_t)4 * 1024 * 2048;       // 4*768*2048
  __bf16* expeb  = palib + (size_t)4 * 768 * 2048;     // 4*256*1024
  __bf16* Vt     = expeb + (size_t)4 * 256 * 1024;     // 4*256*1024 (tile-major: [b][32][256][32])
  __bf16* WqkvpT = Vt + (size_t)4 * 256 * 1024;        // 2560*2048
  __bf16* WqkveT = WqkvpT + (size_t)2560 * 2048;       // 2560*1024
  __bf16* WopT   = WqkveT + (size_t)2560 * 1024;       // 2048*2048
  __bf16* WoeT   = WopT + (size_t)2048 * 2048;         // 1024*2048
  _Float16* maskh = (_Float16*)(WoeT + (size_t)2048 * 1024); // 4*1024*1024 f16

  dim3 blk(256);
  prep_kernel<<<25088, blk, 0, stream>>>(pali, expe, wq_p, wk_p, wv_p, wq_e, wk_e, wv_e,
                                         wo_p, wo_e, mask, palib, expeb, WqkvpT, WqkveT,
                                         WopT, WoeT, maskh);
  gemm_qkv_kernel<<<640, blk, 0, stream>>>(palib, expeb, WqkvpT, WqkveT, QKV);
  rope_trv_kernel<<<2048 + 1024, blk, 0, stream>>>(QKV, pos, Vt);
  attn_mfma_kernel<<<dim3(16, 8, 4), blk, 0, stream>>>(QKV, Vt, maskh, Ab);
  gemm_out_kernel<<<448, blk, 0, stream>>>(Ab, WopT, WoeT, out);
}